// Round 4
// baseline (30380.423 us; speedup 1.0000x reference)
//
#include <hip/hip_runtime.h>

// ---------------- problem constants ----------------
#define B_    32
#define NTOK  197
#define E_    768
#define NH_   12
#define M_    3072
#define L_    12
#define NPAT  196
#define BN    (B_*NTOK)    // 6304
#define BNP   (B_*NPAT)    // 6272

typedef unsigned short bf16_t;

// ---------------- helpers ----------------
__device__ inline float bf2f(bf16_t u){
    union { unsigned int i; float f; } c; c.i = ((unsigned int)u) << 16; return c.f;
}
__device__ inline bf16_t f2bf(float f){
    union { float f; unsigned int i; } c; c.f = f;
    unsigned int u = c.i;
    u += 0x7FFFu + ((u >> 16) & 1u);   // round-to-nearest-even
    return (bf16_t)(u >> 16);
}
__device__ inline float wave_rsum(float x){
    #pragma unroll
    for (int off = 32; off; off >>= 1) x += __shfl_xor(x, off);
    return x;
}
__device__ inline float wave_rmax(float x){
    #pragma unroll
    for (int off = 32; off; off >>= 1) x = fmaxf(x, __shfl_xor(x, off));
    return x;
}

// ---------------- dtype detector: count NaN/Inf bit patterns in bf16 view ----------------
__global__ __launch_bounds__(256) void detect_k(const unsigned short* __restrict__ x,
                                                int n, int* __restrict__ flag){
    int cnt = 0;
    for (int i = blockIdx.x*256 + threadIdx.x; i < n; i += 256*64)
        { unsigned short u = x[i]; if (((u >> 7) & 0xFFu) == 0xFFu) ++cnt; }
    if (cnt) atomicAdd(flag, cnt);
}

// ---------------- input canonicalization to bf16 (flag>=8 means src is f32) ----------------
__global__ __launch_bounds__(256) void convert_k(const void* __restrict__ src,
    bf16_t* __restrict__ dst, int n, const int* __restrict__ flag){
    int i = blockIdx.x*256 + threadIdx.x;
    if (i >= n) return;
    if (*flag >= 8) dst[i] = f2bf(((const float*)src)[i]);
    else            dst[i] = ((const bf16_t*)src)[i];
}

// ---------------- generic tiled GEMM ----------------
// C[M,N] = A @ B (+bias, optional exact GELU). AT: A dtype (0=f32,1=bf16).
// BT=1: B stored [N,K] (C = A@B^T). OT: out dtype (0=f32,1=bf16).
// Requires K%16==0, N%64==0; M-edge guarded.
template<int AT, int BT, int OT, int ACT>
__global__ __launch_bounds__(256) void gemm_ab(
    const void* __restrict__ A, const bf16_t* __restrict__ Bw,
    const bf16_t* __restrict__ bias, void* __restrict__ C,
    int Mr, int Nc, int K)
{
    __shared__ float As[16][72];
    __shared__ float Bs[16][72];
    const int tx = threadIdx.x, ty = threadIdx.y;   // 16x16
    const int t  = ty*16 + tx;
    const int m0 = blockIdx.y*64, n0 = blockIdx.x*64;
    float acc[4][4] = {};

    for (int k0 = 0; k0 < K; k0 += 16){
        {   // A chunk: 64 rows x 16 k
            int mm = t >> 2, kk = (t & 3)*4;
            int row = m0 + mm;
            float f0=0.f,f1=0.f,f2=0.f,f3=0.f;
            if (row < Mr){
                if (AT == 0){
                    const float4 v4 = *(const float4*)((const float*)A + (size_t)row*K + k0 + kk);
                    f0=v4.x; f1=v4.y; f2=v4.z; f3=v4.w;
                } else {
                    const ushort4 u4 = *(const ushort4*)((const bf16_t*)A + (size_t)row*K + k0 + kk);
                    f0=bf2f(u4.x); f1=bf2f(u4.y); f2=bf2f(u4.z); f3=bf2f(u4.w);
                }
            }
            As[kk+0][mm]=f0; As[kk+1][mm]=f1; As[kk+2][mm]=f2; As[kk+3][mm]=f3;
        }
        if (BT){
            int nn = t >> 2, kk = (t & 3)*4;
            const ushort4 u4 = *(const ushort4*)(Bw + (size_t)(n0+nn)*K + k0 + kk);
            Bs[kk+0][nn]=bf2f(u4.x); Bs[kk+1][nn]=bf2f(u4.y);
            Bs[kk+2][nn]=bf2f(u4.z); Bs[kk+3][nn]=bf2f(u4.w);
        } else {
            int kk = t >> 4, nn = (t & 15)*4;
            const ushort4 u4 = *(const ushort4*)(Bw + (size_t)(k0+kk)*Nc + n0 + nn);
            Bs[kk][nn+0]=bf2f(u4.x); Bs[kk][nn+1]=bf2f(u4.y);
            Bs[kk][nn+2]=bf2f(u4.z); Bs[kk][nn+3]=bf2f(u4.w);
        }
        __syncthreads();
        #pragma unroll
        for (int kk = 0; kk < 16; ++kk){
            float4 av = *(const float4*)&As[kk][ty*4];
            float4 bv = *(const float4*)&Bs[kk][tx*4];
            float a_[4] = {av.x, av.y, av.z, av.w};
            float b_[4] = {bv.x, bv.y, bv.z, bv.w};
            #pragma unroll
            for (int i=0;i<4;i++)
                #pragma unroll
                for (int j=0;j<4;j++)
                    acc[i][j] += a_[i]*b_[j];
        }
        __syncthreads();
    }
    #pragma unroll
    for (int i=0;i<4;i++){
        int m = m0 + ty*4 + i;
        if (m >= Mr) continue;
        #pragma unroll
        for (int j=0;j<4;j++){
            int n = n0 + tx*4 + j;
            float v = acc[i][j];
            if (bias) v += bf2f(bias[n]);
            if (ACT==1) v = 0.5f*v*(1.f + erff(v*0.70710678118654752f));
            if (OT == 0) ((float*)C)[(size_t)m*Nc + n] = v;
            else         ((bf16_t*)C)[(size_t)m*Nc + n] = f2bf(v);
        }
    }
}

// ---------------- patchify: x[B,3,224,224](bf16) -> patches[BNP,768](f32) ----------------
__global__ __launch_bounds__(256) void patchify_k(const bf16_t* __restrict__ x, float* __restrict__ out){
    int idx = blockIdx.x*256 + threadIdx.x;
    if (idx >= BNP*E_) return;
    int kk  = idx % 768;
    int bnp = idx / 768;
    int b = bnp / 196, np = bnp % 196;
    int ph = np / 14,  pw = np % 14;
    int c = kk >> 8, rr = kk & 255;
    int i = rr >> 4, j = rr & 15;
    size_t xi = (((size_t)(b*3 + c))*224 + (ph*16 + i))*224 + (pw*16 + j);
    out[idx] = bf2f(x[xi]);
}

// ---------------- assemble h = [cls | patch_emb] + pos (f32) ----------------
__global__ __launch_bounds__(256) void assemble_k(const float* __restrict__ pe,
    const bf16_t* __restrict__ cls, const bf16_t* __restrict__ pos, float* __restrict__ h){
    int idx = blockIdx.x*256 + threadIdx.x;
    if (idx >= BN*E_) return;
    int e = idx % 768; int bn = idx / 768;
    int b = bn / 197,  n  = bn % 197;
    float v = (n == 0) ? bf2f(cls[e]) : pe[((size_t)b*196 + (n-1))*768 + e];
    h[idx] = v + bf2f(pos[n*768 + e]);
}

// ---------------- qkv split + q/k LayerNorm (D=64); q scaled by 1/8 ----------------
// One wave per (token, head). Outputs bf16 [B,H,197,64].
__global__ __launch_bounds__(256) void qkv_split_ln_k(const bf16_t* __restrict__ qkv,
    const bf16_t* __restrict__ qg, const bf16_t* __restrict__ qb,
    const bf16_t* __restrict__ kg, const bf16_t* __restrict__ kb,
    bf16_t* __restrict__ q, bf16_t* __restrict__ k, bf16_t* __restrict__ v){
    int lane = threadIdx.x & 63;
    int item = blockIdx.x*4 + (threadIdx.x >> 6);   // (bn, h) pair, h fastest
    if (item >= BN*NH_) return;                     // wave-uniform
    int bn = item / NH_, h = item % NH_;
    int b = bn / 197,   n = bn % 197;
    size_t src = (size_t)bn*2304 + h*64 + lane;
    size_t dst = (((size_t)(b*NH_ + h))*197 + n)*64 + lane;
    {
        float xv = bf2f(qkv[src]);
        float mu  = wave_rsum(xv) * (1.f/64.f);
        float dd  = xv - mu;
        float var = wave_rsum(dd*dd) * (1.f/64.f);
        q[dst] = f2bf((dd * rsqrtf(var + 1e-5f) * bf2f(qg[lane]) + bf2f(qb[lane])) * 0.125f);
    }
    {
        float xv = bf2f(qkv[src + 768]);
        float mu  = wave_rsum(xv) * (1.f/64.f);
        float dd  = xv - mu;
        float var = wave_rsum(dd*dd) * (1.f/64.f);
        k[dst] = f2bf(dd * rsqrtf(var + 1e-5f) * bf2f(kg[lane]) + bf2f(kb[lane]));
    }
    v[dst] = qkv[src + 1536];    // raw copy
}

// ---------------- attention, one wave per (head, query-row) ----------------
// s_m = sum_d q_d k_md (wave reduce); softmax in registers; P@V via LDS broadcast.
__global__ __launch_bounds__(256) void attn_row_k(const bf16_t* __restrict__ qn,
    const bf16_t* __restrict__ kn, const bf16_t* __restrict__ vn, float* __restrict__ o){
    __shared__ float ply[4][256];
    const int lane = threadIdx.x & 63, wave = threadIdx.x >> 6;
    const int bh = blockIdx.y;
    const int b = bh / NH_, h = bh % NH_;
    const int n = blockIdx.x*4 + wave;
    const int nn = (n < 197) ? n : 196;
    const float q = bf2f(qn[((size_t)bh*197 + nn)*64 + lane]);
    const bf16_t* kb = kn + (size_t)bh*197*64;
    const bf16_t* vb = vn + (size_t)bh*197*64;
    float sreg[4] = {-1e30f,-1e30f,-1e30f,-1e30f};
    for (int m = 0; m < 197; ++m){
        float s = wave_rsum(q * bf2f(kb[(size_t)m*64 + lane]));
        if ((m & 63) == lane) sreg[m >> 6] = s;
    }
    float mx = wave_rmax(fmaxf(fmaxf(sreg[0], sreg[1]), fmaxf(sreg[2], sreg[3])));
    float p[4]; float sum = 0.f;
    #pragma unroll
    for (int t = 0; t < 4; ++t){
        int m = lane + 64*t;
        p[t] = (m < 197) ? expf(sreg[t] - mx) : 0.f;
        sum += p[t];
    }
    sum = wave_rsum(sum);
    float inv = 1.f / sum;
    #pragma unroll
    for (int t = 0; t < 4; ++t) ply[wave][lane + 64*t] = p[t] * inv;
    float acc = 0.f;
    for (int m = 0; m < 197; ++m) acc += ply[wave][m] * bf2f(vb[(size_t)m*64 + lane]);
    if (n < 197) o[((size_t)(b*197 + n))*768 + h*64 + lane] = acc;
}

// ---------------- h[row] += LN(src[row])*g + b  (E=768, f32 src) ----------------
__global__ __launch_bounds__(256) void lnadd_k(const float* __restrict__ src,
    const bf16_t* __restrict__ g, const bf16_t* __restrict__ b, float* __restrict__ h){
    __shared__ float red[256];
    int t = threadIdx.x;
    size_t row = blockIdx.x;
    const float* p = src + row*768;
    float x0 = p[t], x1 = p[t+256], x2 = p[t+512];
    red[t] = x0 + x1 + x2;
    __syncthreads();
    for (int off = 128; off; off >>= 1){ if (t < off) red[t] += red[t+off]; __syncthreads(); }
    float mean = red[0] * (1.f/768.f);
    __syncthreads();
    float d0 = x0-mean, d1 = x1-mean, d2 = x2-mean;
    red[t] = d0*d0 + d1*d1 + d2*d2;
    __syncthreads();
    for (int off = 128; off; off >>= 1){ if (t < off) red[t] += red[t+off]; __syncthreads(); }
    float inv = rsqrtf(red[0]*(1.f/768.f) + 1e-5f);
    float* hp = h + row*768;
    hp[t]     += d0*inv*bf2f(g[t])     + bf2f(b[t]);
    hp[t+256] += d1*inv*bf2f(g[t+256]) + bf2f(b[t+256]);
    hp[t+512] += d2*inv*bf2f(g[t+512]) + bf2f(b[t+512]);
}

// ---------------- output: h[:,0,:] -> FLOAT32 (reference output dtype is f32!) ----------------
__global__ __launch_bounds__(256) void outcopy_k(const float* __restrict__ h, float* __restrict__ out){
    int idx = blockIdx.x*256 + threadIdx.x;
    if (idx >= B_*E_) return;
    int b = idx / 768, e = idx % 768;
    out[idx] = h[(size_t)b*197*768 + e];
}

// ---------------- workspace layout (bytes) ----------------
// [0, 19365888)              h   f32 [6304,768]
// [19365888, 38731776)       t1  f32 [6304,768]
// [38731776, ...)            R region (lifetime-overlapped):
//    qkvbuf  bf16 [6304,2304]  @ R+0      [qkv gemm -> split]
//    patches f32  [6272,768]   @ R+0      [patchify -> embed gemm]
//    projout f32  [6304,768]   @ R+0      [proj gemm -> lnadd]
//    fbuf    bf16 [6304,3072]  @ R+0      [mlp1 -> mlp2]  (overlaps dead qn)
//    qn bf16 @ R+29048832, kn @ +9682944, vn @ +9682944   [split -> attn]
// total = 96,829,440 ; flag @ 96,829,440 ; hedge copies @ 96,829,696
#define OFF_T1   ((size_t)19365888)
#define OFF_R    ((size_t)38731776)
#define OFF_QN   ((size_t)(38731776 + 29048832))        // 67,780,608
#define OFF_KN   ((size_t)(67780608 + 9682944))         // 77,463,552
#define OFF_VN   ((size_t)(77463552 + 9682944))         // 87,146,496
#define OFF_FLAG ((size_t)96829440)
#define OFF_CONV ((size_t)96829696)

extern "C" void kernel_launch(void* const* d_in, const int* in_sizes, int n_in,
                              void* d_out, int out_size, void* d_ws, size_t ws_size,
                              hipStream_t stream) {
    (void)out_size;
    char* wsb = (char*)d_ws;
    float*  h       = (float*)(wsb);
    float*  t1      = (float*)(wsb + OFF_T1);
    bf16_t* qkvbuf  = (bf16_t*)(wsb + OFF_R);
    float*  patches = (float*)(wsb + OFF_R);
    float*  projout = (float*)(wsb + OFF_R);
    bf16_t* fbuf    = (bf16_t*)(wsb + OFF_R);
    bf16_t* qnb     = (bf16_t*)(wsb + OFF_QN);
    bf16_t* knb     = (bf16_t*)(wsb + OFF_KN);
    bf16_t* vnb     = (bf16_t*)(wsb + OFF_VN);
    int*    flag    = (int*)(wsb + OFF_FLAG);

    // Hedge: if ws can hold canonical bf16 copies of every input, detect dtype & convert.
    size_t conv_total = 0;
    for (int i = 0; i < n_in; ++i) conv_total += (((size_t)in_sizes[i]*2) + 15) & ~(size_t)15;
    const bool hedge = (ws_size >= OFF_CONV + conv_total);

    const bf16_t* inp[21];
    if (hedge){
        hipMemsetAsync(flag, 0, 4, stream);
        detect_k<<<64, 256, 0, stream>>>((const unsigned short*)d_in[0], in_sizes[0], flag);
        size_t off = 0;
        for (int i = 0; i < n_in && i < 21; ++i){
            bf16_t* dst = (bf16_t*)(wsb + OFF_CONV + off);
            convert_k<<<(in_sizes[i] + 255)/256, 256, 0, stream>>>(d_in[i], dst, in_sizes[i], flag);
            inp[i] = dst;
            off += (((size_t)in_sizes[i]*2) + 15) & ~(size_t)15;
        }
    } else {
        for (int i = 0; i < n_in && i < 21; ++i) inp[i] = (const bf16_t*)d_in[i];
    }

    dim3 gblk(16, 16);

    // ---- patch embedding ----
    patchify_k<<<(BNP*E_ + 255)/256, 256, 0, stream>>>(inp[0], patches);
    gemm_ab<0,1,0,0><<<dim3(E_/64, BNP/64), gblk, 0, stream>>>(
        patches, inp[1], inp[2], t1, BNP, E_, 768);
    assemble_k<<<(BN*E_ + 255)/256, 256, 0, stream>>>(t1, inp[3], inp[4], h);

    for (int l = 0; l < L_; ++l){
        // qkv = h @ qkv_w + qkv_b  -> bf16
        gemm_ab<0,0,1,0><<<dim3(2304/64, (BN+63)/64), gblk, 0, stream>>>(
            h, inp[5] + (size_t)l*E_*2304, inp[6] + (size_t)l*2304, qkvbuf, BN, 2304, E_);
        // split + LN(q,k), q*=1/8 -> qn,kn,vn bf16 [B,H,197,64]
        qkv_split_ln_k<<<(BN*NH_)/4, 256, 0, stream>>>(
            qkvbuf, inp[7] + l*64, inp[8] + l*64, inp[9] + l*64, inp[10] + l*64,
            qnb, knb, vnb);
        // attention -> t1 (f32)
        attn_row_k<<<dim3(50, B_*NH_), 256, 0, stream>>>(qnb, knb, vnb, t1);
        // proj -> f32
        gemm_ab<0,0,0,0><<<dim3(E_/64, (BN+63)/64), gblk, 0, stream>>>(
            t1, inp[11] + (size_t)l*E_*E_, inp[12] + (size_t)l*E_, projout, BN, E_, E_);
        // h += LN(projout)
        lnadd_k<<<BN, 256, 0, stream>>>(projout, inp[13] + l*E_, inp[14] + l*E_, h);
        // f = gelu(h @ w1 + b1) -> bf16
        gemm_ab<0,0,1,1><<<dim3(M_/64, (BN+63)/64), gblk, 0, stream>>>(
            h, inp[15] + (size_t)l*E_*M_, inp[16] + (size_t)l*M_, fbuf, BN, M_, E_);
        // t1 = f @ w2 + b2 (f32)
        gemm_ab<1,0,0,0><<<dim3(E_/64, (BN+63)/64), gblk, 0, stream>>>(
            fbuf, inp[17] + (size_t)l*M_*E_, inp[18] + (size_t)l*E_, t1, BN, E_, M_);
        // h += LN(t1)
        lnadd_k<<<BN, 256, 0, stream>>>(t1, inp[19] + l*E_, inp[20] + l*E_, h);
    }

    outcopy_k<<<(B_*E_ + 255)/256, 256, 0, stream>>>(h, (float*)d_out);
}